// Round 7
// baseline (250.036 us; speedup 1.0000x reference)
//
#include <hip/hip_runtime.h>
#include <math.h>

// Problem constants
#define Hh   4
#define Bb   8
#define Qq   64
#define Kk   256
#define Dd   256
#define Nn   (Bb * Qq)          // 512
#define GNf  16.0f
#define EPSf 1e-5f

// Row strides: multiples of 32 floats (128 B) so per-t wave loads stay
// 128B-aligned (2 L2 lines). 776/1032 cost mom ~13us (R4/R5 -> R6 proven).
#define SKV  832                // KVb row: [k(256)|v(256)|p(256)|r(4)|pad]
#define SCB  1088               // Cb  row: [q(256)|k(256)|v(256)|p(256)|r(4)|pad]

// ---------------------------------------------------------------------------
struct GemmS { float As[16][136]; float Ws[16][136]; };   // 17408 B
struct RtrS  { float WrT[4][260]; };                      // 4160 B
struct WcbgS { float Wg1s[256][16]; float Ts[256][16]; }; // 32768 B
union  WorkS { GemmS g; RtrS r; };
union  P0S   { GemmS g; RtrS r; WcbgS w; };

// ---------------------------------------------------------------------------
__device__ __forceinline__ float wred(float x) {
#pragma unroll
    for (int off = 32; off > 0; off >>= 1)
        x += __shfl_xor(x, off, 64);
    return x;
}

// ---------------------------------------------------------------------------
// 64x128 tile gemm (validated R1/R3/R6): As transposed pitch-68, Ws
// pitch-136, inner loop = 3 x ds_read_b128 + 32 fma. Prefetch across k0.
__device__ void gemm64(GemmS& g, const float* __restrict__ A, int lda, int Mv,
                       const float* __restrict__ B, int bn,
                       float* __restrict__ C, int ldc)
{
    float (*As)[68] = (float(*)[68])(&g.As[0][0]);
    const int tid = threadIdx.x;
    const int ty = tid >> 4, tx = tid & 15;
    const int am = tid >> 2, ak = (tid & 3) << 2;
    const int wk = tid >> 4, wc = (tid & 15) << 3;
    const int ams = (am < Mv) ? am : (Mv - 1);

    float acc[4][8] = {};
    const float* aptr = A + (size_t)ams * lda + ak;
    const float* bptr = B + wk * 256 + bn + wc;
    float4 av = *(const float4*)aptr;
    float4 b0 = *(const float4*)bptr;
    float4 b1 = *(const float4*)(bptr + 4);

    for (int k0 = 0; k0 < 256; k0 += 16) {
        __syncthreads();
        As[ak + 0][am] = av.x; As[ak + 1][am] = av.y;
        As[ak + 2][am] = av.z; As[ak + 3][am] = av.w;
        *(float4*)&g.Ws[wk][wc]     = b0;
        *(float4*)&g.Ws[wk][wc + 4] = b1;
        __syncthreads();
        if (k0 + 16 < 256) {
            av = *(const float4*)(aptr + k0 + 16);
            b0 = *(const float4*)(bptr + (k0 + 16) * 256);
            b1 = *(const float4*)(bptr + (k0 + 16) * 256 + 4);
        }
#pragma unroll
        for (int kk = 0; kk < 16; ++kk) {
            const float4 a4 = *(const float4*)&As[kk][ty << 2];
            const float4 w0 = *(const float4*)&g.Ws[kk][tx << 2];
            const float4 w1 = *(const float4*)&g.Ws[kk][64 + (tx << 2)];
            const float a_[4] = {a4.x, a4.y, a4.z, a4.w};
            const float w_[8] = {w0.x, w0.y, w0.z, w0.w, w1.x, w1.y, w1.z, w1.w};
#pragma unroll
            for (int i = 0; i < 4; ++i)
#pragma unroll
                for (int jj = 0; jj < 8; ++jj)
                    acc[i][jj] = fmaf(a_[i], w_[jj], acc[i][jj]);
        }
    }

#pragma unroll
    for (int i = 0; i < 4; ++i) {
        const int rr = (ty << 2) + i;
        if (rr < Mv) {
            *(float4*)(C + (size_t)rr * ldc + (tx << 2)) =
                make_float4(acc[i][0], acc[i][1], acc[i][2], acc[i][3]);
            *(float4*)(C + (size_t)rr * ldc + 64 + (tx << 2)) =
                make_float4(acc[i][4], acc[i][5], acc[i][6], acc[i][7]);
        }
    }
}

// ---------------------------------------------------------------------------
// Narrow router region (validated): C(64x4 slice) = A(64x256) @ Wr(256x4).
__device__ void router_region(RtrS& rs, const float* __restrict__ A,
                              const float* __restrict__ Wr,
                              float* __restrict__ C, int ldc, int row0)
{
    const int tid = threadIdx.x;
    for (int idx = tid; idx < 1024; idx += 256)
        rs.WrT[idx & 3][idx >> 2] = Wr[idx];
    __syncthreads();
    const int row = row0 + (tid >> 2), c = tid & 3;
    const float* a = A + (size_t)row * 256;
    float acc = 0.f;
#pragma unroll 8
    for (int k4 = 0; k4 < 64; ++k4) {
        const float4 avv = *(const float4*)(a + (k4 << 2));
        const float4 wvv = *(const float4*)&rs.WrT[c][k4 << 2];
        acc = fmaf(avv.x, wvv.x, acc);
        acc = fmaf(avv.y, wvv.y, acc);
        acc = fmaf(avv.z, wvv.z, acc);
        acc = fmaf(avv.w, wvv.w, acc);
    }
    C[(size_t)row * ldc + c] = acc;
}

// ---------------------------------------------------------------------------
// Wg = W_gk1 @ W_gk2, 16 rows per job (validated).
__device__ void wg_region(const float* __restrict__ Wg1,
                          const float* __restrict__ Wg2,
                          float* __restrict__ Wg, int k0)
{
    const int c = threadIdx.x;
    float w2[16];
#pragma unroll
    for (int i = 0; i < 16; ++i) w2[i] = Wg2[i * 256 + c];
#pragma unroll
    for (int r = 0; r < 16; ++r) {
        const int k = k0 + r;
        float s = 0.f;
#pragma unroll
        for (int i = 0; i < 16; ++i) s = fmaf(Wg1[k * 16 + i], w2[i], s);
        Wg[k * 256 + c] = s;
    }
}

// ---------------------------------------------------------------------------
// Wcb_g = (W_cond @ Wg1) @ Wg2, one 128-col half per block.
// Phase 1: T = W_cond @ Wg1 (256x16) into LDS (Wg1 staged in LDS first).
// Phase 2: Wcb_g[:, colbase..+127] = T @ Wg2 slice; coalesced stores.
__device__ void wcbg_region(WcbgS& w, const float* __restrict__ W_cond,
                            const float* __restrict__ Wg1,
                            const float* __restrict__ Wg2,
                            float* __restrict__ Wcbg, int colbase)
{
    const int tid = threadIdx.x;
    // stage Wg1 (256x16) coalesced
    for (int idx = tid; idx < 4096; idx += 256)
        ((float*)w.Wg1s)[idx] = Wg1[idx];
    __syncthreads();

    // T row tid = W_cond row tid @ Wg1
    {
        float acc[16] = {};
        const float* arow = W_cond + (size_t)tid * 256;
        for (int k4 = 0; k4 < 64; ++k4) {
            const float4 a = *(const float4*)(arow + (k4 << 2));
            const float av[4] = {a.x, a.y, a.z, a.w};
#pragma unroll
            for (int kk = 0; kk < 4; ++kk) {
                const int k = (k4 << 2) + kk;
                const float4 g0 = *(const float4*)&w.Wg1s[k][0];
                const float4 g1 = *(const float4*)&w.Wg1s[k][4];
                const float4 g2 = *(const float4*)&w.Wg1s[k][8];
                const float4 g3 = *(const float4*)&w.Wg1s[k][12];
                acc[0]  = fmaf(av[kk], g0.x, acc[0]);
                acc[1]  = fmaf(av[kk], g0.y, acc[1]);
                acc[2]  = fmaf(av[kk], g0.z, acc[2]);
                acc[3]  = fmaf(av[kk], g0.w, acc[3]);
                acc[4]  = fmaf(av[kk], g1.x, acc[4]);
                acc[5]  = fmaf(av[kk], g1.y, acc[5]);
                acc[6]  = fmaf(av[kk], g1.z, acc[6]);
                acc[7]  = fmaf(av[kk], g1.w, acc[7]);
                acc[8]  = fmaf(av[kk], g2.x, acc[8]);
                acc[9]  = fmaf(av[kk], g2.y, acc[9]);
                acc[10] = fmaf(av[kk], g2.z, acc[10]);
                acc[11] = fmaf(av[kk], g2.w, acc[11]);
                acc[12] = fmaf(av[kk], g3.x, acc[12]);
                acc[13] = fmaf(av[kk], g3.y, acc[13]);
                acc[14] = fmaf(av[kk], g3.z, acc[14]);
                acc[15] = fmaf(av[kk], g3.w, acc[15]);
            }
        }
#pragma unroll
        for (int e4 = 0; e4 < 4; ++e4)
            *(float4*)&w.Ts[tid][e4 << 2] =
                make_float4(acc[e4 * 4], acc[e4 * 4 + 1],
                            acc[e4 * 4 + 2], acc[e4 * 4 + 3]);
    }
    __syncthreads();

    // Wcb_g[r][c] = T[r] . Wg2[:,c];  thread: col c, half the rows
    const int c = colbase + (tid & 127);
    const int r0 = (tid >> 7) * 128;
    float wg2c[16];
#pragma unroll
    for (int e = 0; e < 16; ++e) wg2c[e] = Wg2[e * 256 + c];
    for (int r = r0; r < r0 + 128; ++r) {
        const float4 t0 = *(const float4*)&w.Ts[r][0];
        const float4 t1 = *(const float4*)&w.Ts[r][4];
        const float4 t2 = *(const float4*)&w.Ts[r][8];
        const float4 t3 = *(const float4*)&w.Ts[r][12];
        float s = 0.f;
        s = fmaf(t0.x, wg2c[0],  s); s = fmaf(t0.y, wg2c[1],  s);
        s = fmaf(t0.z, wg2c[2],  s); s = fmaf(t0.w, wg2c[3],  s);
        s = fmaf(t1.x, wg2c[4],  s); s = fmaf(t1.y, wg2c[5],  s);
        s = fmaf(t1.z, wg2c[6],  s); s = fmaf(t1.w, wg2c[7],  s);
        s = fmaf(t2.x, wg2c[8],  s); s = fmaf(t2.y, wg2c[9],  s);
        s = fmaf(t2.z, wg2c[10], s); s = fmaf(t2.w, wg2c[11], s);
        s = fmaf(t3.x, wg2c[12], s); s = fmaf(t3.y, wg2c[13], s);
        s = fmaf(t3.z, wg2c[14], s); s = fmaf(t3.w, wg2c[15], s);
        Wcbg[(size_t)r * 256 + c] = s;
    }
}

// ---------------------------------------------------------------------------
// P0 (46 blocks): fused cond-side weights Wcb_* = W_cond @ {W_q,W_k,W_v,
// Wg1@Wg2, W_router}  plus  Wg = W_gk1 @ W_gk2.  All from raw inputs.
__global__ __launch_bounds__(256) void k_p0(
    const float* __restrict__ W_cond, const float* __restrict__ W_q,
    const float* __restrict__ W_k, const float* __restrict__ W_v,
    const float* __restrict__ W_gk1, const float* __restrict__ W_gk2,
    const float* __restrict__ W_router,
    float* __restrict__ Wcb_q, float* __restrict__ Wcb_k,
    float* __restrict__ Wcb_v, float* __restrict__ Wcb_g,
    float* __restrict__ Wcb_r, float* __restrict__ Wg)
{
    __shared__ P0S S;
    const int id = blockIdx.x;
    if (id < 24) {                               // W_cond @ {W_q,W_k,W_v}
        const int rg = id >> 3, t = id & 7, rt = t >> 1, ct = t & 1;
        const float* Bsel = (rg == 0) ? W_q : (rg == 1) ? W_k : W_v;
        float* Csel = (rg == 0) ? Wcb_q : (rg == 1) ? Wcb_k : Wcb_v;
        gemm64(S.g, W_cond + (size_t)rt * 64 * 256, 256, 64,
               Bsel, ct * 128,
               Csel + (size_t)rt * 64 * 256 + ct * 128, 256);
    } else if (id < 26) {                        // (W_cond@Wg1)@Wg2
        wcbg_region(S.w, W_cond, W_gk1, W_gk2, Wcb_g, (id - 24) * 128);
    } else if (id < 30) {                        // W_cond @ W_router
        router_region(S.r, W_cond, W_router, Wcb_r, 4, (id - 26) * 64);
    } else {                                     // Wg (16 jobs)
        wg_region(W_gk1, W_gk2, Wg, (id - 30) * 16);
    }
}

// ---------------------------------------------------------------------------
// P1 (298 blocks): KVb = keyval @ [W_k|W_v|Wg|W_r]  (2048x832),
// Cb = query @ [Wcb_q|Wcb_k|Wcb_v|Wcb_g|Wcb_r]  (512x1088),
// qlast = keyval[:,255,:] @ W_q  (8x256).  No internal deps.
__global__ __launch_bounds__(256) void k_p1(
    const float* __restrict__ keyval, const float* __restrict__ query,
    const float* __restrict__ W_k, const float* __restrict__ W_v,
    const float* __restrict__ Wg, const float* __restrict__ W_q,
    const float* __restrict__ W_router,
    const float* __restrict__ Wcb_q, const float* __restrict__ Wcb_k,
    const float* __restrict__ Wcb_v, const float* __restrict__ Wcb_g,
    const float* __restrict__ Wcb_r,
    float* __restrict__ KVb, float* __restrict__ Cb,
    float* __restrict__ qlast)
{
    __shared__ WorkS S;
    const int id = blockIdx.x;
    if (id < 192) {                              // KVb k|v|p: 32 rt x 6 ct
        const int rt = id / 6, ct = id % 6;
        const float* Bsel = (ct < 2) ? W_k : (ct < 4) ? W_v : Wg;
        gemm64(S.g, keyval + (size_t)rt * 64 * 256, 256, 64,
               Bsel, (ct & 1) * 128,
               KVb + (size_t)rt * 64 * SKV + (ct >> 1) * 256 + (ct & 1) * 128,
               SKV);
    } else if (id < 224) {                       // KVb router cols
        router_region(S.r, keyval, W_router, KVb + 768, SKV, (id - 192) * 64);
    } else if (id < 288) {                       // Cb main: 4 rg x 8 rt x 2 ct
        const int t = id - 224, rg = t >> 4, tt = t & 15, rt = tt >> 1, ct = tt & 1;
        const float* Bsel = (rg == 0) ? Wcb_q : (rg == 1) ? Wcb_k
                          : (rg == 2) ? Wcb_v : Wcb_g;
        gemm64(S.g, query + (size_t)rt * 64 * 256, 256, 64,
               Bsel, ct * 128,
               Cb + (size_t)rt * 64 * SCB + rg * 256 + ct * 128, SCB);
    } else if (id < 296) {                       // Cb router cols
        router_region(S.r, query, Wcb_r, Cb + 1024, SCB, (id - 288) * 64);
    } else {                                     // qlast (2 jobs)
        gemm64(S.g, keyval + 255 * 256, Kk * Dd, 8, W_q, (id - 296) * 128,
               qlast + (id - 296) * 128, 256);
    }
}

// ---------------------------------------------------------------------------
// mom: R6's validated 73.6us body; dg path moved to native base-2
// (saves the hidden 1.4427/0.693 wrapper muls in the serial chain).
__global__ __launch_bounds__(256) void mom_fused(
    const float* __restrict__ KVb, const float* __restrict__ Cb,
    const float* __restrict__ qlast, const float* __restrict__ b_gk2,
    const int* __restrict__ mask, const float* __restrict__ W_o,
    const float* __restrict__ norm_w, float* __restrict__ out,
    float* __restrict__ logits)
{
    __shared__ float4 wm[Kk];
    __shared__ float  Pt[4][16][68];
    __shared__ float  sbuf[4][16];
    __shared__ float  onorm[Dd];

    const int n = blockIdx.x;
    const int b = n >> 6;
    const int j = threadIdx.x;
    const int lane = j & 63;
    const int wv = j >> 6;

    const float qc = Cb[(size_t)n * SCB + j];
    const float kc = Cb[(size_t)n * SCB + 256 + j];
    const float vc = Cb[(size_t)n * SCB + 512 + j];
    const float pc = Cb[(size_t)n * SCB + 768 + j] + b_gk2[j];
    const float4 rc = *(const float4*)(Cb + (size_t)n * SCB + 1024);

    const int* pm = mask + b * Kk;

    // router top-2 for t = j; logits out; weights to LDS
    {
        const float4 kvr = *(const float4*)(KVb + (size_t)(b * Kk + j) * SKV + 768);
        float l[4] = {kvr.x + rc.x, kvr.y + rc.y, kvr.z + rc.z, kvr.w + rc.w};
        *(float4*)(logits + ((size_t)n * Kk + j) * 4) =
            make_float4(l[0], l[1], l[2], l[3]);

        int i1 = 0;
#pragma unroll
        for (int q = 1; q < 4; ++q) if (l[q] > l[i1]) i1 = q;
        int i2 = -1;
#pragma unroll
        for (int q = 0; q < 4; ++q) {
            if (q == i1) continue;
            if (i2 < 0 || l[q] > l[i2]) i2 = q;
        }
        const float mx = fmaxf(l[i1], l[i2]);
        const float e1 = __expf(l[i1] - mx);
        const float e2 = __expf(l[i2] - mx);
        const float inv = 1.f / (e1 + e2);
        float w[4] = {0.f, 0.f, 0.f, 0.f};
        w[i1] = e1 * inv;
        w[i2] = e2 * inv;
        wm[j] = make_float4(w[0], w[1], w[2], w[3]);
    }
    __syncthreads();

    // reverse-sweep recurrence in 16-t tiles
    const float ql  = qlast[b * 256 + j] + qc;
    const float qkc = ql * kc;
    const float* pk = KVb + (size_t)b * Kk * SKV + j;
    const float* pv = pk + 256;
    const float* pp = pk + 512;

    float E0 = 1.f, E1 = 1.f, E2 = 1.f, E3 = 1.f, E4 = 1.f;
    float o = 0.f;
    const int tl = lane & 15, qg = lane >> 4;

    for (int t0 = Kk - 16; t0 >= 0; t0 -= 16) {
        float vreg[16];
        // phase A: per-t P into LDS tile, no cross-lane ops
#pragma unroll
        for (int i = 0; i < 16; ++i) {
            const int t = t0 + 15 - i;           // descending t
            const float mf   = (float)pm[t];     // wave-uniform
            const float kraw = pk[(size_t)t * SKV];
            const float vraw = pv[(size_t)t * SKV];
            const float praw = pp[(size_t)t * SKV];
            const float pre  = praw + pc;

            // dg = sigmoid(pre)^(mf/16), base-2 native:
            // log2 sig(x) = min(y,0) - log2(1+2^-|y|), y = x*log2(e)
            const float y   = pre * 1.44269504f;
            const float t1  = __builtin_amdgcn_exp2f(-fabsf(y));
            const float ls2 = fminf(y, 0.f) - __builtin_amdgcn_logf(1.f + t1);
            const float dg  = __builtin_amdgcn_exp2f(ls2 * (0.0625f * mf));

            const float4 w  = wm[t];
            const float zf = E0 + w.x * E1 + w.y * E2 + w.z * E3 + w.w * E4;
            Pt[wv][i][lane] = fmaf(ql, kraw, qkc) * zf * mf;
            vreg[i] = vraw + vc;

            E0 *= dg;
            E1 *= (w.x > 0.f) ? dg : 1.f;
            E2 *= (w.y > 0.f) ? dg : 1.f;
            E3 *= (w.z > 0.f) ? dg : 1.f;
            E4 *= (w.w > 0.f) ? dg : 1.f;
        }
        __builtin_amdgcn_wave_barrier();

        // phase B (wave-local): s[i] = sum_c P[i][c]
        float s = 0.f;
#pragma unroll
        for (int rr4 = 0; rr4 < 4; ++rr4) {
            const float4 p4 = *(const float4*)&Pt[wv][tl][qg * 16 + rr4 * 4];
            s += (p4.x + p4.y) + (p4.z + p4.w);
        }
        s += __shfl_xor(s, 16, 64);
        s += __shfl_xor(s, 32, 64);
        sbuf[wv][tl] = s;                        // same-value multi-write, benign
        __builtin_amdgcn_wave_barrier();
#pragma unroll
        for (int rr4 = 0; rr4 < 4; ++rr4) {
            const float4 sv = *(const float4*)&sbuf[wv][rr4 * 4];
            o = fmaf(sv.x, vreg[rr4 * 4 + 0], o);
            o = fmaf(sv.y, vreg[rr4 * 4 + 1], o);
            o = fmaf(sv.z, vreg[rr4 * 4 + 2], o);
            o = fmaf(sv.w, vreg[rr4 * 4 + 3], o);
        }
    }

    // fused RMSNorm over DV (per head = per wave)
    const float ms = wred(o * o) * (1.0f / 64.0f);
    onorm[j] = o * rsqrtf(ms + EPSf) * norm_w[lane];
    __syncthreads();

    // fused output projection: out[n,j] = onorm . W_o[:,j]
    float acc = 0.f;
#pragma unroll 8
    for (int k = 0; k < 256; ++k)
        acc = fmaf(onorm[k], W_o[(size_t)k * 256 + j], acc);
    out[(size_t)n * 256 + j] = acc;
}

// ---------------------------------------------------------------------------
extern "C" void kernel_launch(void* const* d_in, const int* in_sizes, int n_in,
                              void* d_out, int out_size, void* d_ws, size_t ws_size,
                              hipStream_t stream)
{
    const float* query    = (const float*)d_in[0];   // (8,64,256)
    const float* keyval   = (const float*)d_in[1];   // (8,256,256)
    const int*   mask     = (const int*)  d_in[2];   // (8,256)
    const float* W_cond   = (const float*)d_in[3];   // (256,256)
    const float* W_q      = (const float*)d_in[4];   // (256,256)
    const float* W_k      = (const float*)d_in[5];   // (256,256)
    const float* W_v      = (const float*)d_in[6];   // (256,256)
    const float* W_gk1    = (const float*)d_in[7];   // (256,16)
    const float* W_gk2    = (const float*)d_in[8];   // (16,256)
    const float* b_gk2    = (const float*)d_in[9];   // (256,)
    const float* W_router = (const float*)d_in[10];  // (256,4)
    const float* norm_w   = (const float*)d_in[11];  // (64,)
    const float* W_o      = (const float*)d_in[12];  // (256,256)

    float* out    = (float*)d_out;        // (8,64,256)
    float* logits = out + Nn * Dd;        // (N*K, 4)

    // workspace layout (floats)
    float* p = (float*)d_ws;
    float* Wg    = p; p += 256 * 256;       // W_gk1 @ W_gk2
    float* Wcb_q = p; p += 256 * 256;       // W_cond @ W_q
    float* Wcb_k = p; p += 256 * 256;       // W_cond @ W_k
    float* Wcb_v = p; p += 256 * 256;       // W_cond @ W_v
    float* Wcb_g = p; p += 256 * 256;       // (W_cond @ Wg1) @ Wg2
    float* Wcb_r = p; p += 256 * 4;         // W_cond @ W_router
    float* KVb   = p; p += 2048 * SKV;      // keyval @ [k|v|p|r]
    float* qlast = p; p += 8 * 256;         // keyval[:,255,:] @ W_q
    float* Cb    = p; p += Nn * SCB;        // query @ Wcb  (== cond @ [q|k|v|p|r])

    // 1) fused cond-side weights + Wg (46 blocks)
    k_p0<<<46, dim3(256), 0, stream>>>(
        W_cond, W_q, W_k, W_v, W_gk1, W_gk2, W_router,
        Wcb_q, Wcb_k, Wcb_v, Wcb_g, Wcb_r, Wg);

    // 2) KVb + Cb + qlast, one dispatch (298 blocks)
    k_p1<<<298, dim3(256), 0, stream>>>(
        keyval, query, W_k, W_v, Wg, W_q, W_router,
        Wcb_q, Wcb_k, Wcb_v, Wcb_g, Wcb_r, KVb, Cb, qlast);

    // 3) router + recurrence + RMSNorm + output projection
    mom_fused<<<Nn, dim3(256), 0, stream>>>(
        KVb, Cb, qlast, b_gk2, mask, W_o, norm_w, out, logits);
}

// Round 8
// 204.374 us; speedup vs baseline: 1.2234x; 1.2234x over previous
//
#include <hip/hip_runtime.h>
#include <math.h>

// Problem constants
#define Hh   4
#define Bb   8
#define Qq   64
#define Kk   256
#define Dd   256
#define Nn   (Bb * Qq)          // 512
#define GNf  16.0f
#define EPSf 1e-5f

// KVb row stride: multiple of 32 floats (128 B) so per-t wave loads stay
// 128B-aligned (2 L2 lines). Misaligned strides cost mom ~13us (R4/R5->R6).
#define SKV  832                // KVb row: [k(256)|v(256)|p(256)|r(4)|pad]

// ---------------------------------------------------------------------------
struct GemmS { float As[16][136]; float Ws[16][136]; };   // 17408 B
struct RtrS  { float WrT[4][260]; };                      // 4160 B
struct WcbgS { float Wg1s[256][16]; float Ts[256][16]; }; // 32768 B
union  PrepS { GemmS g; RtrS r; WcbgS w; };

// ---------------------------------------------------------------------------
__device__ __forceinline__ float wred(float x) {
#pragma unroll
    for (int off = 32; off > 0; off >>= 1)
        x += __shfl_xor(x, off, 64);
    return x;
}

// ---------------------------------------------------------------------------
// 64x128 tile gemm (validated R1/R3/R6/R7): As transposed pitch-68, Ws
// pitch-136, inner loop = 3 x ds_read_b128 + 32 fma. Prefetch across k0.
__device__ void gemm64(GemmS& g, const float* __restrict__ A, int lda, int Mv,
                       const float* __restrict__ B, int bn,
                       float* __restrict__ C, int ldc)
{
    float (*As)[68] = (float(*)[68])(&g.As[0][0]);
    const int tid = threadIdx.x;
    const int ty = tid >> 4, tx = tid & 15;
    const int am = tid >> 2, ak = (tid & 3) << 2;
    const int wk = tid >> 4, wc = (tid & 15) << 3;
    const int ams = (am < Mv) ? am : (Mv - 1);

    float acc[4][8] = {};
    const float* aptr = A + (size_t)ams * lda + ak;
    const float* bptr = B + wk * 256 + bn + wc;
    float4 av = *(const float4*)aptr;
    float4 b0 = *(const float4*)bptr;
    float4 b1 = *(const float4*)(bptr + 4);

    for (int k0 = 0; k0 < 256; k0 += 16) {
        __syncthreads();
        As[ak + 0][am] = av.x; As[ak + 1][am] = av.y;
        As[ak + 2][am] = av.z; As[ak + 3][am] = av.w;
        *(float4*)&g.Ws[wk][wc]     = b0;
        *(float4*)&g.Ws[wk][wc + 4] = b1;
        __syncthreads();
        if (k0 + 16 < 256) {
            av = *(const float4*)(aptr + k0 + 16);
            b0 = *(const float4*)(bptr + (k0 + 16) * 256);
            b1 = *(const float4*)(bptr + (k0 + 16) * 256 + 4);
        }
#pragma unroll
        for (int kk = 0; kk < 16; ++kk) {
            const float4 a4 = *(const float4*)&As[kk][ty << 2];
            const float4 w0 = *(const float4*)&g.Ws[kk][tx << 2];
            const float4 w1 = *(const float4*)&g.Ws[kk][64 + (tx << 2)];
            const float a_[4] = {a4.x, a4.y, a4.z, a4.w};
            const float w_[8] = {w0.x, w0.y, w0.z, w0.w, w1.x, w1.y, w1.z, w1.w};
#pragma unroll
            for (int i = 0; i < 4; ++i)
#pragma unroll
                for (int jj = 0; jj < 8; ++jj)
                    acc[i][jj] = fmaf(a_[i], w_[jj], acc[i][jj]);
        }
    }

#pragma unroll
    for (int i = 0; i < 4; ++i) {
        const int rr = (ty << 2) + i;
        if (rr < Mv) {
            *(float4*)(C + (size_t)rr * ldc + (tx << 2)) =
                make_float4(acc[i][0], acc[i][1], acc[i][2], acc[i][3]);
            *(float4*)(C + (size_t)rr * ldc + 64 + (tx << 2)) =
                make_float4(acc[i][4], acc[i][5], acc[i][6], acc[i][7]);
        }
    }
}

// ---------------------------------------------------------------------------
// Narrow router region (validated): C(rows x 4 slice) = A(64x256)@Wr(256x4).
__device__ void router_region(RtrS& rs, const float* __restrict__ A,
                              const float* __restrict__ Wr,
                              float* __restrict__ C, int ldc, int row0)
{
    const int tid = threadIdx.x;
    for (int idx = tid; idx < 1024; idx += 256)
        rs.WrT[idx & 3][idx >> 2] = Wr[idx];
    __syncthreads();
    const int row = row0 + (tid >> 2), c = tid & 3;
    const float* a = A + (size_t)row * 256;
    float acc = 0.f;
#pragma unroll 8
    for (int k4 = 0; k4 < 64; ++k4) {
        const float4 avv = *(const float4*)(a + (k4 << 2));
        const float4 wvv = *(const float4*)&rs.WrT[c][k4 << 2];
        acc = fmaf(avv.x, wvv.x, acc);
        acc = fmaf(avv.y, wvv.y, acc);
        acc = fmaf(avv.z, wvv.z, acc);
        acc = fmaf(avv.w, wvv.w, acc);
    }
    C[(size_t)row * ldc + c] = acc;
}

// ---------------------------------------------------------------------------
// Wcb_g = (W_cond @ Wg1) @ Wg2, one 128-col half per block (validated R7).
__device__ void wcbg_region(WcbgS& w, const float* __restrict__ W_cond,
                            const float* __restrict__ Wg1,
                            const float* __restrict__ Wg2,
                            float* __restrict__ Wcbg, int colbase)
{
    const int tid = threadIdx.x;
    for (int idx = tid; idx < 4096; idx += 256)
        ((float*)w.Wg1s)[idx] = Wg1[idx];
    __syncthreads();

    {
        float acc[16] = {};
        const float* arow = W_cond + (size_t)tid * 256;
        for (int k4 = 0; k4 < 64; ++k4) {
            const float4 a = *(const float4*)(arow + (k4 << 2));
            const float av[4] = {a.x, a.y, a.z, a.w};
#pragma unroll
            for (int kk = 0; kk < 4; ++kk) {
                const int k = (k4 << 2) + kk;
                const float4 g0 = *(const float4*)&w.Wg1s[k][0];
                const float4 g1 = *(const float4*)&w.Wg1s[k][4];
                const float4 g2 = *(const float4*)&w.Wg1s[k][8];
                const float4 g3 = *(const float4*)&w.Wg1s[k][12];
                acc[0]  = fmaf(av[kk], g0.x, acc[0]);
                acc[1]  = fmaf(av[kk], g0.y, acc[1]);
                acc[2]  = fmaf(av[kk], g0.z, acc[2]);
                acc[3]  = fmaf(av[kk], g0.w, acc[3]);
                acc[4]  = fmaf(av[kk], g1.x, acc[4]);
                acc[5]  = fmaf(av[kk], g1.y, acc[5]);
                acc[6]  = fmaf(av[kk], g1.z, acc[6]);
                acc[7]  = fmaf(av[kk], g1.w, acc[7]);
                acc[8]  = fmaf(av[kk], g2.x, acc[8]);
                acc[9]  = fmaf(av[kk], g2.y, acc[9]);
                acc[10] = fmaf(av[kk], g2.z, acc[10]);
                acc[11] = fmaf(av[kk], g2.w, acc[11]);
                acc[12] = fmaf(av[kk], g3.x, acc[12]);
                acc[13] = fmaf(av[kk], g3.y, acc[13]);
                acc[14] = fmaf(av[kk], g3.z, acc[14]);
                acc[15] = fmaf(av[kk], g3.w, acc[15]);
            }
        }
#pragma unroll
        for (int e4 = 0; e4 < 4; ++e4)
            *(float4*)&w.Ts[tid][e4 << 2] =
                make_float4(acc[e4 * 4], acc[e4 * 4 + 1],
                            acc[e4 * 4 + 2], acc[e4 * 4 + 3]);
    }
    __syncthreads();

    const int c = colbase + (tid & 127);
    const int r0 = (tid >> 7) * 128;
    float wg2c[16];
#pragma unroll
    for (int e = 0; e < 16; ++e) wg2c[e] = Wg2[e * 256 + c];
    for (int r = r0; r < r0 + 128; ++r) {
        const float4 t0 = *(const float4*)&w.Ts[r][0];
        const float4 t1 = *(const float4*)&w.Ts[r][4];
        const float4 t2 = *(const float4*)&w.Ts[r][8];
        const float4 t3 = *(const float4*)&w.Ts[r][12];
        float s = 0.f;
        s = fmaf(t0.x, wg2c[0],  s); s = fmaf(t0.y, wg2c[1],  s);
        s = fmaf(t0.z, wg2c[2],  s); s = fmaf(t0.w, wg2c[3],  s);
        s = fmaf(t1.x, wg2c[4],  s); s = fmaf(t1.y, wg2c[5],  s);
        s = fmaf(t1.z, wg2c[6],  s); s = fmaf(t1.w, wg2c[7],  s);
        s = fmaf(t2.x, wg2c[8],  s); s = fmaf(t2.y, wg2c[9],  s);
        s = fmaf(t2.z, wg2c[10], s); s = fmaf(t2.w, wg2c[11], s);
        s = fmaf(t3.x, wg2c[12], s); s = fmaf(t3.y, wg2c[13], s);
        s = fmaf(t3.z, wg2c[14], s); s = fmaf(t3.w, wg2c[15], s);
        Wcbg[(size_t)r * 256 + c] = s;
    }
}

// ---------------------------------------------------------------------------
// KVb p-columns for one 64-row keyval tile, from raw Wg1/Wg2 (no Wg dep):
// T = tile @ Wg1 (64x16) via 4-way k-split partials, then C = T @ Wg2.
__device__ void kvp_region(WcbgS& w, const float* __restrict__ A,  // 64x256
                           const float* __restrict__ Wg1,
                           const float* __restrict__ Wg2,
                           float* __restrict__ C, int ldc)
{
    const int tid = threadIdx.x;
    for (int idx = tid; idx < 4096; idx += 256)
        ((float*)w.Wg1s)[idx] = Wg1[idx];
    __syncthreads();

    // partial T: thread (r = tid&63, q = tid>>6) covers k in [64q, 64q+64)
    {
        const int r = tid & 63, q = tid >> 6;
        float acc[16] = {};
        const float* arow = A + (size_t)r * 256 + q * 64;
        for (int k4 = 0; k4 < 16; ++k4) {
            const float4 a = *(const float4*)(arow + (k4 << 2));
            const float av[4] = {a.x, a.y, a.z, a.w};
#pragma unroll
            for (int kk = 0; kk < 4; ++kk) {
                const int k = q * 64 + (k4 << 2) + kk;
                const float4 g0 = *(const float4*)&w.Wg1s[k][0];
                const float4 g1 = *(const float4*)&w.Wg1s[k][4];
                const float4 g2 = *(const float4*)&w.Wg1s[k][8];
                const float4 g3 = *(const float4*)&w.Wg1s[k][12];
                acc[0]  = fmaf(av[kk], g0.x, acc[0]);
                acc[1]  = fmaf(av[kk], g0.y, acc[1]);
                acc[2]  = fmaf(av[kk], g0.z, acc[2]);
                acc[3]  = fmaf(av[kk], g0.w, acc[3]);
                acc[4]  = fmaf(av[kk], g1.x, acc[4]);
                acc[5]  = fmaf(av[kk], g1.y, acc[5]);
                acc[6]  = fmaf(av[kk], g1.z, acc[6]);
                acc[7]  = fmaf(av[kk], g1.w, acc[7]);
                acc[8]  = fmaf(av[kk], g2.x, acc[8]);
                acc[9]  = fmaf(av[kk], g2.y, acc[9]);
                acc[10] = fmaf(av[kk], g2.z, acc[10]);
                acc[11] = fmaf(av[kk], g2.w, acc[11]);
                acc[12] = fmaf(av[kk], g3.x, acc[12]);
                acc[13] = fmaf(av[kk], g3.y, acc[13]);
                acc[14] = fmaf(av[kk], g3.z, acc[14]);
                acc[15] = fmaf(av[kk], g3.w, acc[15]);
            }
        }
#pragma unroll
        for (int e4 = 0; e4 < 4; ++e4)
            *(float4*)&w.Ts[q * 64 + r][e4 << 2] =
                make_float4(acc[e4 * 4], acc[e4 * 4 + 1],
                            acc[e4 * 4 + 2], acc[e4 * 4 + 3]);
    }
    __syncthreads();

    // combine partials: thread (r = tid>>2, e4 = (tid&3)*4) sums 4 slots into
    // Ts[r][e4..+3]. Each quad written by exactly the thread that reads it.
    {
        const int r = tid >> 2, e4 = (tid & 3) << 2;
        const float4 s0 = *(const float4*)&w.Ts[r][e4];
        const float4 s1 = *(const float4*)&w.Ts[64 + r][e4];
        const float4 s2 = *(const float4*)&w.Ts[128 + r][e4];
        const float4 s3 = *(const float4*)&w.Ts[192 + r][e4];
        *(float4*)&w.Ts[r][e4] =
            make_float4(s0.x + s1.x + s2.x + s3.x, s0.y + s1.y + s2.y + s3.y,
                        s0.z + s1.z + s2.z + s3.z, s0.w + s1.w + s2.w + s3.w);
    }
    __syncthreads();

    // phase 2: col c = tid; 64 rows; stores coalesced per row
    {
        const int c = tid;
        float wg2c[16];
#pragma unroll
        for (int e = 0; e < 16; ++e) wg2c[e] = Wg2[e * 256 + c];
        for (int r = 0; r < 64; ++r) {
            const float4 t0 = *(const float4*)&w.Ts[r][0];
            const float4 t1 = *(const float4*)&w.Ts[r][4];
            const float4 t2 = *(const float4*)&w.Ts[r][8];
            const float4 t3 = *(const float4*)&w.Ts[r][12];
            float s = 0.f;
            s = fmaf(t0.x, wg2c[0],  s); s = fmaf(t0.y, wg2c[1],  s);
            s = fmaf(t0.z, wg2c[2],  s); s = fmaf(t0.w, wg2c[3],  s);
            s = fmaf(t1.x, wg2c[4],  s); s = fmaf(t1.y, wg2c[5],  s);
            s = fmaf(t1.z, wg2c[6],  s); s = fmaf(t1.w, wg2c[7],  s);
            s = fmaf(t2.x, wg2c[8],  s); s = fmaf(t2.y, wg2c[9],  s);
            s = fmaf(t2.z, wg2c[10], s); s = fmaf(t2.w, wg2c[11], s);
            s = fmaf(t3.x, wg2c[12], s); s = fmaf(t3.y, wg2c[13], s);
            s = fmaf(t3.z, wg2c[14], s); s = fmaf(t3.w, wg2c[15], s);
            C[(size_t)r * ldc + c] = s;
        }
    }
}

// ---------------------------------------------------------------------------
// k_prep (224 blocks): EVERYTHING from raw inputs, one dispatch.
__global__ __launch_bounds__(256) void k_prep(
    const float* __restrict__ keyval, const float* __restrict__ W_cond,
    const float* __restrict__ W_q, const float* __restrict__ W_k,
    const float* __restrict__ W_v, const float* __restrict__ W_gk1,
    const float* __restrict__ W_gk2, const float* __restrict__ W_router,
    float* __restrict__ KVb, float* __restrict__ Wcb_q,
    float* __restrict__ Wcb_k, float* __restrict__ Wcb_v,
    float* __restrict__ Wcb_g, float* __restrict__ Wcb_r,
    float* __restrict__ qlast)
{
    __shared__ PrepS S;
    const int id = blockIdx.x;
    if (id < 128) {                              // KVb k|v: 32 rt x 2 mat x 2 ct
        const int rt = id >> 2, sub = id & 3, mat = sub >> 1, ct = sub & 1;
        gemm64(S.g, keyval + (size_t)rt * 64 * 256, 256, 64,
               mat ? W_v : W_k, ct * 128,
               KVb + (size_t)rt * 64 * SKV + mat * 256 + ct * 128, SKV);
    } else if (id < 160) {                       // KVb p: (tile@Wg1)@Wg2
        const int rt = id - 128;
        kvp_region(S.w, keyval + (size_t)rt * 64 * 256, W_gk1, W_gk2,
                   KVb + (size_t)rt * 64 * SKV + 512, SKV);
    } else if (id < 192) {                       // KVb router cols
        router_region(S.r, keyval, W_router, KVb + 768, SKV, (id - 160) * 64);
    } else if (id < 216) {                       // Wcb_q/k/v = W_cond @ ...
        const int t = id - 192, rg = t >> 3, tt = t & 7, rt = tt >> 1, ct = tt & 1;
        const float* Bsel = (rg == 0) ? W_q : (rg == 1) ? W_k : W_v;
        float* Csel = (rg == 0) ? Wcb_q : (rg == 1) ? Wcb_k : Wcb_v;
        gemm64(S.g, W_cond + (size_t)rt * 64 * 256, 256, 64,
               Bsel, ct * 128, Csel + (size_t)rt * 64 * 256 + ct * 128, 256);
    } else if (id < 218) {                       // Wcb_g = (W_cond@Wg1)@Wg2
        wcbg_region(S.w, W_cond, W_gk1, W_gk2, Wcb_g, (id - 216) * 128);
    } else if (id < 222) {                       // Wcb_r = W_cond @ W_router
        router_region(S.r, W_cond, W_router, Wcb_r, 4, (id - 218) * 64);
    } else {                                     // qlast (2 jobs)
        gemm64(S.g, keyval + 255 * 256, Kk * Dd, 8, W_q, (id - 222) * 128,
               qlast + (id - 222) * 128, 256);
    }
}

// ---------------------------------------------------------------------------
// mom_v2: R7-validated recurrence body + inline Cb (query[n] @ Wcb_*) via
// LDS-staged column dots (Pt reused as 16KB staging buffer before the
// recurrence needs it), rc via wave-reduce + cross-wave LDS combine.
__global__ __launch_bounds__(256) void mom_fused(
    const float* __restrict__ KVb, const float* __restrict__ query,
    const float* __restrict__ Wcb_q, const float* __restrict__ Wcb_k,
    const float* __restrict__ Wcb_v, const float* __restrict__ Wcb_g,
    const float* __restrict__ Wcb_r, const float* __restrict__ qlast,
    const float* __restrict__ b_gk2, const int* __restrict__ mask,
    const float* __restrict__ W_o, const float* __restrict__ norm_w,
    float* __restrict__ out, float* __restrict__ logits)
{
    __shared__ float4 wm[Kk];
    __shared__ __align__(16) float Pt[4][16][68];   // 4352 floats; staging buf
    __shared__ float  sbuf[4][16];
    __shared__ float  onorm[Dd];
    __shared__ float  qs[Dd];
    __shared__ float4 rred[4];

    const int n = blockIdx.x;
    const int b = n >> 6;
    const int j = threadIdx.x;
    const int lane = j & 63;
    const int wv = j >> 6;

    qs[j] = query[(size_t)n * 256 + j];
    __syncthreads();

    // ---- inline Cb: qc,kc,vc,pcv = query[n] . Wcb_*[:,j], 16-row chunks
    float qc = 0.f, kc = 0.f, vc = 0.f, pcv = 0.f;
    float* stg = &Pt[0][0][0];
#define CB_DOT(Wm, accv)                                                 \
    for (int k0 = 0; k0 < 256; k0 += 16) {                               \
        __syncthreads();                                                 \
        const float4* src = (const float4*)(Wm) + (k0 << 6);             \
        float4* dst = (float4*)stg;                                      \
        dst[j]       = src[j];                                           \
        dst[j + 256] = src[j + 256];                                     \
        dst[j + 512] = src[j + 512];                                     \
        dst[j + 768] = src[j + 768];                                     \
        __syncthreads();                                                 \
        _Pragma("unroll")                                                \
        for (int kk = 0; kk < 16; ++kk)                                  \
            accv = fmaf(qs[k0 + kk], stg[kk * 256 + j], accv);           \
    }
    CB_DOT(Wcb_q, qc)
    CB_DOT(Wcb_k, kc)
    CB_DOT(Wcb_v, vc)
    CB_DOT(Wcb_g, pcv)
#undef CB_DOT
    const float pc = pcv + b_gk2[j];

    // ---- rc = query[n] @ Wcb_r (4 floats): wave-reduce + LDS combine
    {
        const float4 wr4 = *(const float4*)(Wcb_r + (size_t)j * 4);
        const float qj = qs[j];
        float4 pr;
        pr.x = wred(qj * wr4.x);
        pr.y = wred(qj * wr4.y);
        pr.z = wred(qj * wr4.z);
        pr.w = wred(qj * wr4.w);
        if (lane == 0) rred[wv] = pr;
    }
    __syncthreads();
    const float4 r0_ = rred[0], r1_ = rred[1], r2_ = rred[2], r3_ = rred[3];
    const float4 rc = make_float4(r0_.x + r1_.x + r2_.x + r3_.x,
                                  r0_.y + r1_.y + r2_.y + r3_.y,
                                  r0_.z + r1_.z + r2_.z + r3_.z,
                                  r0_.w + r1_.w + r2_.w + r3_.w);

    const int* pm = mask + b * Kk;

    // ---- router top-2 for t = j; logits out; weights to LDS
    {
        const float4 kvr = *(const float4*)(KVb + (size_t)(b * Kk + j) * SKV + 768);
        float l[4] = {kvr.x + rc.x, kvr.y + rc.y, kvr.z + rc.z, kvr.w + rc.w};
        *(float4*)(logits + ((size_t)n * Kk + j) * 4) =
            make_float4(l[0], l[1], l[2], l[3]);

        int i1 = 0;
#pragma unroll
        for (int q = 1; q < 4; ++q) if (l[q] > l[i1]) i1 = q;
        int i2 = -1;
#pragma unroll
        for (int q = 0; q < 4; ++q) {
            if (q == i1) continue;
            if (i2 < 0 || l[q] > l[i2]) i2 = q;
        }
        const float mx = fmaxf(l[i1], l[i2]);
        const float e1 = __expf(l[i1] - mx);
        const float e2 = __expf(l[i2] - mx);
        const float inv = 1.f / (e1 + e2);
        float w[4] = {0.f, 0.f, 0.f, 0.f};
        w[i1] = e1 * inv;
        w[i2] = e2 * inv;
        wm[j] = make_float4(w[0], w[1], w[2], w[3]);
    }
    __syncthreads();   // also protects Pt reuse below

    // ---- reverse-sweep recurrence in 16-t tiles (R7-validated)
    const float ql  = qlast[b * 256 + j] + qc;
    const float qkc = ql * kc;
    const float* pk = KVb + (size_t)b * Kk * SKV + j;
    const float* pv = pk + 256;
    const float* pp = pk + 512;

    float E0 = 1.f, E1 = 1.f, E2 = 1.f, E3 = 1.f, E4 = 1.f;
    float o = 0.f;
    const int tl = lane & 15, qg = lane >> 4;

    for (int t0 = Kk - 16; t0 >= 0; t0 -= 16) {
        float vreg[16];
#pragma unroll
        for (int i = 0; i < 16; ++i) {
            const int t = t0 + 15 - i;           // descending t
            const float mf   = (float)pm[t];     // wave-uniform
            const float kraw = pk[(size_t)t * SKV];
            const float vraw = pv[(size_t)t * SKV];
            const float praw = pp[(size_t)t * SKV];
            const float pre  = praw + pc;

            // dg = sigmoid(pre)^(mf/16), base-2 native
            const float y   = pre * 1.44269504f;
            const float t1  = __builtin_amdgcn_exp2f(-fabsf(y));
            const float ls2 = fminf(y, 0.f) - __builtin_amdgcn_logf(1.f + t1);
            const float dg  = __builtin_amdgcn_exp2f(ls2 * (0.0625f * mf));

            const float4 w  = wm[t];
            const float zf = E0 + w.x * E1 + w.y * E2 + w.z * E3 + w.w * E4;
            Pt[wv][i][lane] = fmaf(ql, kraw, qkc) * zf * mf;
            vreg[i] = vraw + vc;

            E0 *= dg;
            E1 *= (w.x > 0.f) ? dg : 1.f;
            E2 *= (w.y > 0.f) ? dg : 1.f;
            E3 *= (w.z > 0.f) ? dg : 1.f;
            E4 *= (w.w > 0.f) ? dg : 1.f;
        }
        __builtin_amdgcn_wave_barrier();

        float s = 0.f;
#pragma unroll
        for (int rr4 = 0; rr4 < 4; ++rr4) {
            const float4 p4 = *(const float4*)&Pt[wv][tl][qg * 16 + rr4 * 4];
            s += (p4.x + p4.y) + (p4.z + p4.w);
        }
        s += __shfl_xor(s, 16, 64);
        s += __shfl_xor(s, 32, 64);
        sbuf[wv][tl] = s;                        // same-value multi-write, benign
        __builtin_amdgcn_wave_barrier();
#pragma unroll
        for (int rr4 = 0; rr4 < 4; ++rr4) {
            const float4 sv = *(const float4*)&sbuf[wv][rr4 * 4];
            o = fmaf(sv.x, vreg[rr4 * 4 + 0], o);
            o = fmaf(sv.y, vreg[rr4 * 4 + 1], o);
            o = fmaf(sv.z, vreg[rr4 * 4 + 2], o);
            o = fmaf(sv.w, vreg[rr4 * 4 + 3], o);
        }
    }

    // ---- fused RMSNorm over DV (per head = per wave)
    const float ms = wred(o * o) * (1.0f / 64.0f);
    onorm[j] = o * rsqrtf(ms + EPSf) * norm_w[lane];
    __syncthreads();

    // ---- fused output projection: out[n,j] = onorm . W_o[:,j]
    float acc = 0.f;
#pragma unroll 8
    for (int k = 0; k < 256; ++k)
        acc = fmaf(onorm[k], W_o[(size_t)k * 256 + j], acc);
    out[(size_t)n * 256 + j] = acc;
}

// ---------------------------------------------------------------------------
extern "C" void kernel_launch(void* const* d_in, const int* in_sizes, int n_in,
                              void* d_out, int out_size, void* d_ws, size_t ws_size,
                              hipStream_t stream)
{
    const float* query    = (const float*)d_in[0];   // (8,64,256)
    const float* keyval   = (const float*)d_in[1];   // (8,256,256)
    const int*   mask     = (const int*)  d_in[2];   // (8,256)
    const float* W_cond   = (const float*)d_in[3];   // (256,256)
    const float* W_q      = (const float*)d_in[4];   // (256,256)
    const float* W_k      = (const float*)d_in[5];   // (256,256)
    const float* W_v      = (const float*)d_in[6];   // (256,256)
    const float* W_gk1    = (const float*)d_in[7];   // (256,16)
    const float* W_gk2    = (const float*)d_in[8];   // (16,256)
    const float* b_gk2    = (const float*)d_in[9];   // (256,)
    const float* W_router = (const float*)d_in[10];  // (256,4)
    const float* norm_w   = (const float*)d_in[11];  // (64,)
    const float* W_o      = (const float*)d_in[12];  // (256,256)

    float* out    = (float*)d_out;        // (8,64,256)
    float* logits = out + Nn * Dd;        // (N*K, 4)

    // workspace layout (floats)
    float* p = (float*)d_ws;
    float* KVb   = p; p += 2048 * SKV;      // keyval @ [k|v|p|r]
    float* Wcb_q = p; p += 256 * 256;       // W_cond @ W_q
    float* Wcb_k = p; p += 256 * 256;       // W_cond @ W_k
    float* Wcb_v = p; p += 256 * 256;       // W_cond @ W_v
    float* Wcb_g = p; p += 256 * 256;       // (W_cond @ Wg1) @ Wg2
    float* Wcb_r = p; p += 256 * 4;         // W_cond @ W_router
    float* qlast = p; p += 8 * 256;         // keyval[:,255,:] @ W_q

    // 1) everything from raw inputs, one dispatch (224 blocks)
    k_prep<<<224, dim3(256), 0, stream>>>(
        keyval, W_cond, W_q, W_k, W_v, W_gk1, W_gk2, W_router,
        KVb, Wcb_q, Wcb_k, Wcb_v, Wcb_g, Wcb_r, qlast);

    // 2) mom with inline Cb (512 blocks)
    mom_fused<<<Nn, dim3(256), 0, stream>>>(
        KVb, query, Wcb_q, Wcb_k, Wcb_v, Wcb_g, Wcb_r, qlast,
        b_gk2, mask, W_o, norm_w, out, logits);
}